// Round 12
// baseline (329.573 us; speedup 1.0000x reference)
//
#include <hip/hip_runtime.h>
#include <hip/hip_bf16.h>
#include <stdint.h>

// SynAlign R12 — LOCALIZATION ROUND: exact R9 kernel set (246.0 us baseline), with
// pv_kernel launched TWICE (idempotent). dur - 246 == isolated K3 time.
//  K1 pool_kernel : 4096 blocks (XCD-swizzled), 16 rows/block rolling window.
//  K2 score_kernel: 256 blocks x 512 thr, dk=64, score overlays chunk pool, dual softmax.
//  K3 pv_kernel   : 4096 blocks (XCD-swizzled), VT_LD=138, P16 A-frags, NT stores.

#define SL 128
#define DIM 1024

#define OFF_S     ((size_t)0)
#define OFF_SATT  ((size_t)33554432)
#define OFF_ATSM  ((size_t)67108864)
#define OFF_T     ((size_t)71303168)
#define OFF_TATT  ((size_t)104857600)
#define OFF_TASM  ((size_t)138412032)
#define SIDE_ELEMS ((size_t)33554432)           // bf16 sidecar elems per side
#define PHALF      ((size_t)4194304)            // elems per bf16 soft matrix
#define WS_NEEDED   ((size_t)134217728)         // s/t sidecar bytes
#define WS_P_NEEDED ((size_t)150994944)         // + P sidecar

typedef short bf16x8 __attribute__((ext_vector_type(8)));
typedef float f32x4 __attribute__((ext_vector_type(4)));
typedef unsigned short u16;

#define CH2   72   // K2 chunk row stride (bf16): 64 data + 8 pad
#define SC_LD 136  // score row stride (bf16): 128 data + 8 pad
#define VT_LD 138  // K3 V^T row stride (bf16): conflict-free staging writes

__device__ __forceinline__ u16 f2bf(float f) {
  union { float f; uint32_t u; } v; v.f = f;
  uint32_t r = (v.u + 0x7FFFu + ((v.u >> 16) & 1u)) >> 16;  // RNE
  return (u16)r;
}
__device__ __forceinline__ float bf2f(u16 h) {
  union { uint32_t u; float f; } v; v.u = ((uint32_t)h) << 16;
  return v.f;
}

// ---------------- K1: gather + avgpool3, 16 rows/block rolling window ----------------
__global__ __launch_bounds__(256) void pool_kernel(
    const int* __restrict__ ssent, const int* __restrict__ tsent,
    const float* __restrict__ semb, const float* __restrict__ temb,
    float* __restrict__ out, u16* __restrict__ ws16, int use_ws)
{
  const int raw = blockIdx.x;
  const int bid = (raw & 7) * 512 + (raw >> 3);   // XCD swizzle (4096 % 8 == 0)
  const int side = bid >> 11;
  const int rem = bid & 2047;
  const int b = rem >> 3;
  const int l0 = (rem & 7) * 16;
  const int tid = threadIdx.x;

  const int* __restrict__ sent = side ? tsent : ssent;
  const float* __restrict__ emb = side ? temb : semb;
  float* __restrict__ dst0 = out + (side ? OFF_T : OFF_S) + ((size_t)b * SL + l0) * DIM;
  u16* __restrict__ d16_0 = ws16 + (side ? SIDE_ELEMS : 0) + ((size_t)b * SL + l0) * DIM;

  const int sbase = b * SL + l0;
  float4 ePrev, eCur, eNext;
  if (l0 > 0) ePrev = ((const float4*)(emb + (size_t)sent[sbase - 1] * DIM))[tid];
  else        ePrev = (float4){0.f, 0.f, 0.f, 0.f};
  eCur = ((const float4*)(emb + (size_t)sent[sbase] * DIM))[tid];

  #pragma unroll
  for (int i = 0; i < 16; ++i) {
    const int l = l0 + i;
    if (l + 1 < SL)
      eNext = ((const float4*)(emb + (size_t)sent[sbase + i + 1] * DIM))[tid];
    else
      eNext = (float4){0.f, 0.f, 0.f, 0.f};
    const float scl = (l == 0 || l == SL - 1) ? 0.5f : (1.0f / 3.0f);
    f32x4 o;
    o[0] = (ePrev.x + eCur.x + eNext.x) * scl;
    o[1] = (ePrev.y + eCur.y + eNext.y) * scl;
    o[2] = (ePrev.z + eCur.z + eNext.z) * scl;
    o[3] = (ePrev.w + eCur.w + eNext.w) * scl;
    __builtin_nontemporal_store(o, ((f32x4*)(dst0 + (size_t)i * DIM)) + tid);
    if (use_ws) {
      ushort4 h;
      h.x = f2bf(o[0]); h.y = f2bf(o[1]); h.z = f2bf(o[2]); h.w = f2bf(o[3]);
      ((ushort4*)(d16_0 + (size_t)i * DIM))[tid] = h;   // cached: re-read by K2/K3
    }
    ePrev = eCur; eCur = eNext;
  }
}

// ---------------- K2: score (once) + dual softmax, dk=64 ----------------
__global__ __launch_bounds__(512) void score_kernel(
    const int* __restrict__ smask, const int* __restrict__ tmask,
    float* __restrict__ out, u16* __restrict__ ws16, int use_ws, int use_p16)
{
  // chunk pool (36,864 B); score [SL][SC_LD] (34,816 B) OVERLAYS it after the K-loop
  __shared__ __align__(16) u16 chunkpool[2 * SL * CH2];
  __shared__ float part[2][4][SL];
  __shared__ float rowmax[SL], rowinv[SL], colmax[SL], colinv[SL];
  __shared__ float maskT[SL], maskS[SL];

  u16* const a_chunk = chunkpool;             // t rows [SL][CH2]
  u16* const b_chunk = chunkpool + SL * CH2;  // s rows [SL][CH2]
  u16* const score   = chunkpool;             // [SL][SC_LD] after K-loop

  const int b = blockIdx.x;
  const int tid = threadIdx.x;
  const int lane = tid & 63;
  const int w = tid >> 6;

  const float* t_base = out + OFF_T + (size_t)b * SL * DIM;
  const float* s_base = out + OFF_S + (size_t)b * SL * DIM;
  float* ta_base = out + OFF_TASM + (size_t)b * SL * SL;
  float* at_base = out + OFF_ATSM + (size_t)b * SL * SL;
  u16* taP = ws16 + 2 * SIDE_ELEMS + (size_t)b * SL * SL;
  u16* atP = ws16 + 2 * SIDE_ELEMS + PHALF + (size_t)b * SL * SL;

  if (tid < SL) maskT[tid] = (tmask[b * SL + tid] != 0) ? 1.0f : 0.0f;
  else if (tid < 2 * SL) maskS[tid - SL] = (smask[b * SL + (tid - SL)] != 0) ? 1.0f : 0.0f;

  f32x4 acc[8];
  #pragma unroll
  for (int nt = 0; nt < 8; ++nt) acc[nt] = (f32x4){0.f, 0.f, 0.f, 0.f};

  const int srow = tid >> 2;        // 0..127
  const int seg = tid & 3;          // 0..3
  const size_t a_src = SIDE_ELEMS + ((size_t)b * SL + srow) * DIM + seg * 8;  // t
  const size_t b_src = ((size_t)b * SL + srow) * DIM + seg * 8;               // s
  u16* const a_dst = &a_chunk[srow * CH2 + seg * 8];
  u16* const b_dst = &b_chunk[srow * CH2 + seg * 8];

  uint4 ra0, ra1, rb0, rb1;

  if (use_ws) {
    ra0 = *(const uint4*)(ws16 + a_src);
    ra1 = *(const uint4*)(ws16 + a_src + 32);
    rb0 = *(const uint4*)(ws16 + b_src);
    rb1 = *(const uint4*)(ws16 + b_src + 32);
  }

  for (int it = 0; it < 16; ++it) {
    const int dk = it * 64;
    if (use_ws) {
      *(uint4*)a_dst = ra0;
      *(uint4*)(a_dst + 32) = ra1;
      *(uint4*)b_dst = rb0;
      *(uint4*)(b_dst + 32) = rb1;
    } else {
      #pragma unroll
      for (int c = 0; c < 2; ++c) {
        const float* ap = t_base + (size_t)srow * DIM + dk + c * 32 + seg * 8;
        const float* bp = s_base + (size_t)srow * DIM + dk + c * 32 + seg * 8;
        float4 va0 = ((const float4*)ap)[0], va1 = ((const float4*)ap)[1];
        float4 vb0 = ((const float4*)bp)[0], vb1 = ((const float4*)bp)[1];
        bf16x8 ha, hb;
        ha[0]=(short)f2bf(va0.x); ha[1]=(short)f2bf(va0.y); ha[2]=(short)f2bf(va0.z); ha[3]=(short)f2bf(va0.w);
        ha[4]=(short)f2bf(va1.x); ha[5]=(short)f2bf(va1.y); ha[6]=(short)f2bf(va1.z); ha[7]=(short)f2bf(va1.w);
        hb[0]=(short)f2bf(vb0.x); hb[1]=(short)f2bf(vb0.y); hb[2]=(short)f2bf(vb0.z); hb[3]=(short)f2bf(vb0.w);
        hb[4]=(short)f2bf(vb1.x); hb[5]=(short)f2bf(vb1.y); hb[6]=(short)f2bf(vb1.z); hb[7]=(short)f2bf(vb1.w);
        *(bf16x8*)(a_dst + c * 32) = ha;
        *(bf16x8*)(b_dst + c * 32) = hb;
      }
    }
    __syncthreads();

    if (use_ws && it + 1 < 16) {   // prefetch next chunk, hides under ds_read+MFMA
      const int dk2 = dk + 64;
      ra0 = *(const uint4*)(ws16 + a_src + dk2);
      ra1 = *(const uint4*)(ws16 + a_src + dk2 + 32);
      rb0 = *(const uint4*)(ws16 + b_src + dk2);
      rb1 = *(const uint4*)(ws16 + b_src + dk2 + 32);
    }

    #pragma unroll
    for (int ks = 0; ks < 2; ++ks) {
      const int colb = ks * 32 + (lane >> 4) * 8;
      const bf16x8 afr = *(const bf16x8*)&a_chunk[(w * 16 + (lane & 15)) * CH2 + colb];
      #pragma unroll
      for (int nt = 0; nt < 8; ++nt) {
        const bf16x8 bfr = *(const bf16x8*)&b_chunk[(nt * 16 + (lane & 15)) * CH2 + colb];
        acc[nt] = __builtin_amdgcn_mfma_f32_16x16x32_bf16(afr, bfr, acc[nt], 0, 0, 0);
      }
    }
    __syncthreads();
  }

  // masked score -> LDS (overlays dead chunk pool). col=lane&15, row=(lane>>4)*4+j
  #pragma unroll
  for (int nt = 0; nt < 8; ++nt) {
    const int coln = nt * 16 + (lane & 15);
    const float cm = maskS[coln];
    #pragma unroll
    for (int j = 0; j < 4; ++j) {
      const int rowm = w * 16 + (lane >> 4) * 4 + j;
      const float val = (cm != 0.0f && maskT[rowm] != 0.0f) ? acc[nt][j] : -999.0f;
      score[rowm * SC_LD + coln] = f2bf(val);
    }
  }
  __syncthreads();

  // ---- parallel 4-way softmax stats ----
  const int rc = tid & 127;
  const int q = tid >> 7;
  {
    float mx = -1e30f;
    #pragma unroll
    for (int c8 = 0; c8 < 4; ++c8) {
      const uint4 v = *(const uint4*)&score[rc * SC_LD + q * 32 + c8 * 8];
      mx = fmaxf(mx, fmaxf(bf2f((u16)(v.x & 0xffff)), bf2f((u16)(v.x >> 16))));
      mx = fmaxf(mx, fmaxf(bf2f((u16)(v.y & 0xffff)), bf2f((u16)(v.y >> 16))));
      mx = fmaxf(mx, fmaxf(bf2f((u16)(v.z & 0xffff)), bf2f((u16)(v.z >> 16))));
      mx = fmaxf(mx, fmaxf(bf2f((u16)(v.w & 0xffff)), bf2f((u16)(v.w >> 16))));
    }
    part[0][q][rc] = mx;
    float mc = -1e30f;
    #pragma unroll 8
    for (int r = q * 32; r < q * 32 + 32; ++r)
      mc = fmaxf(mc, bf2f(score[r * SC_LD + rc]));
    part[1][q][rc] = mc;
  }
  __syncthreads();
  if (tid < SL) {
    rowmax[tid] = fmaxf(fmaxf(part[0][0][tid], part[0][1][tid]),
                        fmaxf(part[0][2][tid], part[0][3][tid]));
  } else if (tid < 2 * SL) {
    const int c = tid - SL;
    colmax[c] = fmaxf(fmaxf(part[1][0][c], part[1][1][c]),
                      fmaxf(part[1][2][c], part[1][3][c]));
  }
  __syncthreads();
  {
    const float mR = rowmax[rc];
    float sm = 0.0f;
    #pragma unroll
    for (int c8 = 0; c8 < 4; ++c8) {
      const uint4 v = *(const uint4*)&score[rc * SC_LD + q * 32 + c8 * 8];
      sm += __expf(bf2f((u16)(v.x & 0xffff)) - mR) + __expf(bf2f((u16)(v.x >> 16)) - mR);
      sm += __expf(bf2f((u16)(v.y & 0xffff)) - mR) + __expf(bf2f((u16)(v.y >> 16)) - mR);
      sm += __expf(bf2f((u16)(v.z & 0xffff)) - mR) + __expf(bf2f((u16)(v.z >> 16)) - mR);
      sm += __expf(bf2f((u16)(v.w & 0xffff)) - mR) + __expf(bf2f((u16)(v.w >> 16)) - mR);
    }
    part[0][q][rc] = sm;
    const float mC = colmax[rc];
    float sc = 0.0f;
    #pragma unroll 8
    for (int r = q * 32; r < q * 32 + 32; ++r)
      sc += __expf(bf2f(score[r * SC_LD + rc]) - mC);
    part[1][q][rc] = sc;
  }
  __syncthreads();
  if (tid < SL) {
    rowinv[tid] = 1.0f / (part[0][0][tid] + part[0][1][tid] + part[0][2][tid] + part[0][3][tid]);
  } else if (tid < 2 * SL) {
    const int c = tid - SL;
    colinv[c] = 1.0f / (part[1][0][c] + part[1][1][c] + part[1][2][c] + part[1][3][c]);
  }
  __syncthreads();

  for (int idx = tid; idx < SL * SL; idx += 512) {
    const int r = idx >> 7, c = idx & 127;
    const float tv = __expf(bf2f(score[r * SC_LD + c]) - rowmax[r]) * rowinv[r];
    const float av = __expf(bf2f(score[c * SC_LD + r]) - colmax[r]) * colinv[r];
    __builtin_nontemporal_store(tv, &ta_base[idx]);
    __builtin_nontemporal_store(av, &at_base[idx]);
    if (use_p16) {
      taP[idx] = f2bf(tv);
      atP[idx] = f2bf(av);
    }
  }
}

// ---------------- K3: PV GEMM ----------------
__global__ __launch_bounds__(256) void pv_kernel(
    float* __restrict__ out, u16* __restrict__ ws16, int use_ws, int use_p16)
{
  __shared__ __align__(16) u16 vt[SL * VT_LD];   // V^T [n][k], 35,328 B

  const int raw = blockIdx.x;
  const int bid = (raw & 7) * 512 + (raw >> 3);  // bijective: 4096 % 8 == 0
  const int ntile = bid & 7;
  const int b = (bid >> 3) & 255;
  const int ori = bid >> 11;
  const int tid = threadIdx.x;
  const int lane = tid & 63;
  const int w = tid >> 6;

  const float* p_base = out + (ori ? OFF_ATSM : OFF_TASM) + (size_t)b * SL * SL;
  const u16* p16_base = ws16 + 2 * SIDE_ELEMS + (ori ? PHALF : (size_t)0) + (size_t)b * SL * SL;
  float* att_base = out + (ori ? OFF_TATT : OFF_SATT) + (size_t)b * SL * DIM + ntile * 128;

  // stage V^T tile; VT_LD=138 -> oct groups at banks +0/+8/+16/+24 (free)
  #pragma unroll
  for (int j = 0; j < 8; ++j) {
    const int idx = tid + j * 256;
    const int k = (idx & 15) | ((idx >> 8) << 4);
    const int oct = (idx >> 4) & 15;
    if (use_ws) {
      const u16* src = ws16 + (ori ? SIDE_ELEMS : 0)
                     + ((size_t)b * SL + k) * DIM + ntile * 128 + oct * 8;
      uint4 v = *(const uint4*)src;
      const u16* ev = (const u16*)&v;
      #pragma unroll
      for (int i = 0; i < 8; ++i) vt[(oct * 8 + i) * VT_LD + k] = ev[i];
    } else {
      const float* src = out + (ori ? OFF_T : OFF_S)
                       + ((size_t)b * SL + k) * DIM + ntile * 128 + oct * 8;
      float4 v0 = ((const float4*)src)[0];
      float4 v1 = ((const float4*)src)[1];
      vt[(oct * 8 + 0) * VT_LD + k] = f2bf(v0.x);
      vt[(oct * 8 + 1) * VT_LD + k] = f2bf(v0.y);
      vt[(oct * 8 + 2) * VT_LD + k] = f2bf(v0.z);
      vt[(oct * 8 + 3) * VT_LD + k] = f2bf(v0.w);
      vt[(oct * 8 + 4) * VT_LD + k] = f2bf(v1.x);
      vt[(oct * 8 + 5) * VT_LD + k] = f2bf(v1.y);
      vt[(oct * 8 + 6) * VT_LD + k] = f2bf(v1.z);
      vt[(oct * 8 + 7) * VT_LD + k] = f2bf(v1.w);
    }
  }

  // A-fragments (P): single 16B bf16 loads from sidecar (L2/L3-hot)
  bf16x8 afr[2][4];
  #pragma unroll
  for (int mt = 0; mt < 2; ++mt) {
    const int m = w * 32 + mt * 16 + (lane & 15);
    #pragma unroll
    for (int ks = 0; ks < 4; ++ks) {
      const int k0 = ks * 32 + (lane >> 4) * 8;
      if (use_p16) {
        afr[mt][ks] = *(const bf16x8*)(p16_base + (size_t)m * SL + k0);
      } else {
        const float* pp = p_base + (size_t)m * SL + k0;
        float4 x0 = ((const float4*)pp)[0];
        float4 x1 = ((const float4*)pp)[1];
        bf16x8 a;
        a[0] = (short)f2bf(x0.x); a[1] = (short)f2bf(x0.y);
        a[2] = (short)f2bf(x0.z); a[3] = (short)f2bf(x0.w);
        a[4] = (short)f2bf(x1.x); a[5] = (short)f2bf(x1.y);
        a[6] = (short)f2bf(x1.z); a[7] = (short)f2bf(x1.w);
        afr[mt][ks] = a;
      }
    }
  }
  __syncthreads();

  f32x4 acc[2][8];
  #pragma unroll
  for (int mt = 0; mt < 2; ++mt)
    #pragma unroll
    for (int nt = 0; nt < 8; ++nt)
      acc[mt][nt] = (f32x4){0.f, 0.f, 0.f, 0.f};

  const int colb = (lane >> 4) * 8;
  #pragma unroll
  for (int ks = 0; ks < 4; ++ks) {
    #pragma unroll
    for (int nt = 0; nt < 8; ++nt) {
      const bf16x8 bfr = *(const bf16x8*)&vt[(nt * 16 + (lane & 15)) * VT_LD + ks * 32 + colb];
      acc[0][nt] = __builtin_amdgcn_mfma_f32_16x16x32_bf16(afr[0][ks], bfr, acc[0][nt], 0, 0, 0);
      acc[1][nt] = __builtin_amdgcn_mfma_f32_16x16x32_bf16(afr[1][ks], bfr, acc[1][nt], 0, 0, 0);
    }
  }

  #pragma unroll
  for (int mt = 0; mt < 2; ++mt)
    #pragma unroll
    for (int nt = 0; nt < 8; ++nt) {
      const int rowm = w * 32 + mt * 16 + (lane >> 4) * 4;
      #pragma unroll
      for (int j = 0; j < 4; ++j)
        __builtin_nontemporal_store(acc[mt][nt][j],
            &att_base[(size_t)(rowm + j) * DIM + nt * 16 + (lane & 15)]);
    }
}

extern "C" void kernel_launch(void* const* d_in, const int* in_sizes, int n_in,
                              void* d_out, int out_size, void* d_ws, size_t ws_size,
                              hipStream_t stream) {
  const int* ssent = (const int*)d_in[0];
  const int* tsent = (const int*)d_in[1];
  const int* smask = (const int*)d_in[2];
  const int* tmask = (const int*)d_in[3];
  const float* semb = (const float*)d_in[4];
  const float* temb = (const float*)d_in[5];
  float* out = (float*)d_out;
  u16* ws16 = (u16*)d_ws;
  const int use_ws = (ws_size >= WS_NEEDED) ? 1 : 0;
  const int use_p16 = (ws_size >= WS_P_NEEDED) ? 1 : 0;

  hipLaunchKernelGGL(pool_kernel, dim3(4096), dim3(256), 0, stream,
                     ssent, tsent, semb, temb, out, ws16, use_ws);
  hipLaunchKernelGGL(score_kernel, dim3(256), dim3(512), 0, stream,
                     smask, tmask, out, ws16, use_ws, use_p16);
  // LOCALIZATION: K3 launched twice (idempotent). dur - 246us == isolated K3 time.
  hipLaunchKernelGGL(pv_kernel, dim3(4096), dim3(256), 0, stream, out, ws16, use_ws, use_p16);
  hipLaunchKernelGGL(pv_kernel, dim3(4096), dim3(256), 0, stream, out, ws16, use_ws, use_p16);
}

// Round 13
// 266.805 us; speedup vs baseline: 1.2353x; 1.2353x over previous
//
#include <hip/hip_runtime.h>
#include <hip/hip_bf16.h>
#include <stdint.h>

// SynAlign R13: R9 pipeline + K3 wide-store epilogue (LDS transpose).
//  K1 pool_kernel : 4096 blocks (XCD-swizzled), 16 rows/block rolling window.
//  K2 score_kernel: 256 blocks x 512 thr, dk=64, score overlays chunk pool, dual softmax.
//  K3 pv_kernel   : 4096 blocks (XCD-swizzled), VT_LD=138, P16 A-frags;
//                   NEW: acc -> LDS (overlaying dead vt) -> float4 NT stores
//                   (256B-dense per wave-instr instead of 4x64B scalar segments).

#define SL 128
#define DIM 1024

#define OFF_S     ((size_t)0)
#define OFF_SATT  ((size_t)33554432)
#define OFF_ATSM  ((size_t)67108864)
#define OFF_T     ((size_t)71303168)
#define OFF_TATT  ((size_t)104857600)
#define OFF_TASM  ((size_t)138412032)
#define SIDE_ELEMS ((size_t)33554432)           // bf16 sidecar elems per side
#define PHALF      ((size_t)4194304)            // elems per bf16 soft matrix
#define WS_NEEDED   ((size_t)134217728)         // s/t sidecar bytes
#define WS_P_NEEDED ((size_t)150994944)         // + P sidecar

typedef short bf16x8 __attribute__((ext_vector_type(8)));
typedef float f32x4 __attribute__((ext_vector_type(4)));
typedef unsigned short u16;

#define CH2   72   // K2 chunk row stride (bf16): 64 data + 8 pad
#define SC_LD 136  // score row stride (bf16): 128 data + 8 pad
#define VT_LD 138  // K3 V^T row stride (bf16): conflict-free staging writes
#define SB_LD 72   // K3 epilogue fp32 row stride: 64 data + 8 pad

__device__ __forceinline__ u16 f2bf(float f) {
  union { float f; uint32_t u; } v; v.f = f;
  uint32_t r = (v.u + 0x7FFFu + ((v.u >> 16) & 1u)) >> 16;  // RNE
  return (u16)r;
}
__device__ __forceinline__ float bf2f(u16 h) {
  union { uint32_t u; float f; } v; v.u = ((uint32_t)h) << 16;
  return v.f;
}

// ---------------- K1: gather + avgpool3, 16 rows/block rolling window ----------------
__global__ __launch_bounds__(256) void pool_kernel(
    const int* __restrict__ ssent, const int* __restrict__ tsent,
    const float* __restrict__ semb, const float* __restrict__ temb,
    float* __restrict__ out, u16* __restrict__ ws16, int use_ws)
{
  const int raw = blockIdx.x;
  const int bid = (raw & 7) * 512 + (raw >> 3);   // XCD swizzle (4096 % 8 == 0)
  const int side = bid >> 11;
  const int rem = bid & 2047;
  const int b = rem >> 3;
  const int l0 = (rem & 7) * 16;
  const int tid = threadIdx.x;

  const int* __restrict__ sent = side ? tsent : ssent;
  const float* __restrict__ emb = side ? temb : semb;
  float* __restrict__ dst0 = out + (side ? OFF_T : OFF_S) + ((size_t)b * SL + l0) * DIM;
  u16* __restrict__ d16_0 = ws16 + (side ? SIDE_ELEMS : 0) + ((size_t)b * SL + l0) * DIM;

  const int sbase = b * SL + l0;
  float4 ePrev, eCur, eNext;
  if (l0 > 0) ePrev = ((const float4*)(emb + (size_t)sent[sbase - 1] * DIM))[tid];
  else        ePrev = (float4){0.f, 0.f, 0.f, 0.f};
  eCur = ((const float4*)(emb + (size_t)sent[sbase] * DIM))[tid];

  #pragma unroll
  for (int i = 0; i < 16; ++i) {
    const int l = l0 + i;
    if (l + 1 < SL)
      eNext = ((const float4*)(emb + (size_t)sent[sbase + i + 1] * DIM))[tid];
    else
      eNext = (float4){0.f, 0.f, 0.f, 0.f};
    const float scl = (l == 0 || l == SL - 1) ? 0.5f : (1.0f / 3.0f);
    f32x4 o;
    o[0] = (ePrev.x + eCur.x + eNext.x) * scl;
    o[1] = (ePrev.y + eCur.y + eNext.y) * scl;
    o[2] = (ePrev.z + eCur.z + eNext.z) * scl;
    o[3] = (ePrev.w + eCur.w + eNext.w) * scl;
    __builtin_nontemporal_store(o, ((f32x4*)(dst0 + (size_t)i * DIM)) + tid);
    if (use_ws) {
      ushort4 h;
      h.x = f2bf(o[0]); h.y = f2bf(o[1]); h.z = f2bf(o[2]); h.w = f2bf(o[3]);
      ((ushort4*)(d16_0 + (size_t)i * DIM))[tid] = h;   // cached: re-read by K2/K3
    }
    ePrev = eCur; eCur = eNext;
  }
}

// ---------------- K2: score (once) + dual softmax, dk=64 ----------------
__global__ __launch_bounds__(512) void score_kernel(
    const int* __restrict__ smask, const int* __restrict__ tmask,
    float* __restrict__ out, u16* __restrict__ ws16, int use_ws, int use_p16)
{
  // chunk pool (36,864 B); score [SL][SC_LD] (34,816 B) OVERLAYS it after the K-loop
  __shared__ __align__(16) u16 chunkpool[2 * SL * CH2];
  __shared__ float part[2][4][SL];
  __shared__ float rowmax[SL], rowinv[SL], colmax[SL], colinv[SL];
  __shared__ float maskT[SL], maskS[SL];

  u16* const a_chunk = chunkpool;             // t rows [SL][CH2]
  u16* const b_chunk = chunkpool + SL * CH2;  // s rows [SL][CH2]
  u16* const score   = chunkpool;             // [SL][SC_LD] after K-loop

  const int b = blockIdx.x;
  const int tid = threadIdx.x;
  const int lane = tid & 63;
  const int w = tid >> 6;

  const float* t_base = out + OFF_T + (size_t)b * SL * DIM;
  const float* s_base = out + OFF_S + (size_t)b * SL * DIM;
  float* ta_base = out + OFF_TASM + (size_t)b * SL * SL;
  float* at_base = out + OFF_ATSM + (size_t)b * SL * SL;
  u16* taP = ws16 + 2 * SIDE_ELEMS + (size_t)b * SL * SL;
  u16* atP = ws16 + 2 * SIDE_ELEMS + PHALF + (size_t)b * SL * SL;

  if (tid < SL) maskT[tid] = (tmask[b * SL + tid] != 0) ? 1.0f : 0.0f;
  else if (tid < 2 * SL) maskS[tid - SL] = (smask[b * SL + (tid - SL)] != 0) ? 1.0f : 0.0f;

  f32x4 acc[8];
  #pragma unroll
  for (int nt = 0; nt < 8; ++nt) acc[nt] = (f32x4){0.f, 0.f, 0.f, 0.f};

  const int srow = tid >> 2;        // 0..127
  const int seg = tid & 3;          // 0..3
  const size_t a_src = SIDE_ELEMS + ((size_t)b * SL + srow) * DIM + seg * 8;  // t
  const size_t b_src = ((size_t)b * SL + srow) * DIM + seg * 8;               // s
  u16* const a_dst = &a_chunk[srow * CH2 + seg * 8];
  u16* const b_dst = &b_chunk[srow * CH2 + seg * 8];

  uint4 ra0, ra1, rb0, rb1;

  if (use_ws) {
    ra0 = *(const uint4*)(ws16 + a_src);
    ra1 = *(const uint4*)(ws16 + a_src + 32);
    rb0 = *(const uint4*)(ws16 + b_src);
    rb1 = *(const uint4*)(ws16 + b_src + 32);
  }

  for (int it = 0; it < 16; ++it) {
    const int dk = it * 64;
    if (use_ws) {
      *(uint4*)a_dst = ra0;
      *(uint4*)(a_dst + 32) = ra1;
      *(uint4*)b_dst = rb0;
      *(uint4*)(b_dst + 32) = rb1;
    } else {
      #pragma unroll
      for (int c = 0; c < 2; ++c) {
        const float* ap = t_base + (size_t)srow * DIM + dk + c * 32 + seg * 8;
        const float* bp = s_base + (size_t)srow * DIM + dk + c * 32 + seg * 8;
        float4 va0 = ((const float4*)ap)[0], va1 = ((const float4*)ap)[1];
        float4 vb0 = ((const float4*)bp)[0], vb1 = ((const float4*)bp)[1];
        bf16x8 ha, hb;
        ha[0]=(short)f2bf(va0.x); ha[1]=(short)f2bf(va0.y); ha[2]=(short)f2bf(va0.z); ha[3]=(short)f2bf(va0.w);
        ha[4]=(short)f2bf(va1.x); ha[5]=(short)f2bf(va1.y); ha[6]=(short)f2bf(va1.z); ha[7]=(short)f2bf(va1.w);
        hb[0]=(short)f2bf(vb0.x); hb[1]=(short)f2bf(vb0.y); hb[2]=(short)f2bf(vb0.z); hb[3]=(short)f2bf(vb0.w);
        hb[4]=(short)f2bf(vb1.x); hb[5]=(short)f2bf(vb1.y); hb[6]=(short)f2bf(vb1.z); hb[7]=(short)f2bf(vb1.w);
        *(bf16x8*)(a_dst + c * 32) = ha;
        *(bf16x8*)(b_dst + c * 32) = hb;
      }
    }
    __syncthreads();

    if (use_ws && it + 1 < 16) {   // prefetch next chunk, hides under ds_read+MFMA
      const int dk2 = dk + 64;
      ra0 = *(const uint4*)(ws16 + a_src + dk2);
      ra1 = *(const uint4*)(ws16 + a_src + dk2 + 32);
      rb0 = *(const uint4*)(ws16 + b_src + dk2);
      rb1 = *(const uint4*)(ws16 + b_src + dk2 + 32);
    }

    #pragma unroll
    for (int ks = 0; ks < 2; ++ks) {
      const int colb = ks * 32 + (lane >> 4) * 8;
      const bf16x8 afr = *(const bf16x8*)&a_chunk[(w * 16 + (lane & 15)) * CH2 + colb];
      #pragma unroll
      for (int nt = 0; nt < 8; ++nt) {
        const bf16x8 bfr = *(const bf16x8*)&b_chunk[(nt * 16 + (lane & 15)) * CH2 + colb];
        acc[nt] = __builtin_amdgcn_mfma_f32_16x16x32_bf16(afr, bfr, acc[nt], 0, 0, 0);
      }
    }
    __syncthreads();
  }

  // masked score -> LDS (overlays dead chunk pool). col=lane&15, row=(lane>>4)*4+j
  #pragma unroll
  for (int nt = 0; nt < 8; ++nt) {
    const int coln = nt * 16 + (lane & 15);
    const float cm = maskS[coln];
    #pragma unroll
    for (int j = 0; j < 4; ++j) {
      const int rowm = w * 16 + (lane >> 4) * 4 + j;
      const float val = (cm != 0.0f && maskT[rowm] != 0.0f) ? acc[nt][j] : -999.0f;
      score[rowm * SC_LD + coln] = f2bf(val);
    }
  }
  __syncthreads();

  // ---- parallel 4-way softmax stats ----
  const int rc = tid & 127;
  const int q = tid >> 7;
  {
    float mx = -1e30f;
    #pragma unroll
    for (int c8 = 0; c8 < 4; ++c8) {
      const uint4 v = *(const uint4*)&score[rc * SC_LD + q * 32 + c8 * 8];
      mx = fmaxf(mx, fmaxf(bf2f((u16)(v.x & 0xffff)), bf2f((u16)(v.x >> 16))));
      mx = fmaxf(mx, fmaxf(bf2f((u16)(v.y & 0xffff)), bf2f((u16)(v.y >> 16))));
      mx = fmaxf(mx, fmaxf(bf2f((u16)(v.z & 0xffff)), bf2f((u16)(v.z >> 16))));
      mx = fmaxf(mx, fmaxf(bf2f((u16)(v.w & 0xffff)), bf2f((u16)(v.w >> 16))));
    }
    part[0][q][rc] = mx;
    float mc = -1e30f;
    #pragma unroll 8
    for (int r = q * 32; r < q * 32 + 32; ++r)
      mc = fmaxf(mc, bf2f(score[r * SC_LD + rc]));
    part[1][q][rc] = mc;
  }
  __syncthreads();
  if (tid < SL) {
    rowmax[tid] = fmaxf(fmaxf(part[0][0][tid], part[0][1][tid]),
                        fmaxf(part[0][2][tid], part[0][3][tid]));
  } else if (tid < 2 * SL) {
    const int c = tid - SL;
    colmax[c] = fmaxf(fmaxf(part[1][0][c], part[1][1][c]),
                      fmaxf(part[1][2][c], part[1][3][c]));
  }
  __syncthreads();
  {
    const float mR = rowmax[rc];
    float sm = 0.0f;
    #pragma unroll
    for (int c8 = 0; c8 < 4; ++c8) {
      const uint4 v = *(const uint4*)&score[rc * SC_LD + q * 32 + c8 * 8];
      sm += __expf(bf2f((u16)(v.x & 0xffff)) - mR) + __expf(bf2f((u16)(v.x >> 16)) - mR);
      sm += __expf(bf2f((u16)(v.y & 0xffff)) - mR) + __expf(bf2f((u16)(v.y >> 16)) - mR);
      sm += __expf(bf2f((u16)(v.z & 0xffff)) - mR) + __expf(bf2f((u16)(v.z >> 16)) - mR);
      sm += __expf(bf2f((u16)(v.w & 0xffff)) - mR) + __expf(bf2f((u16)(v.w >> 16)) - mR);
    }
    part[0][q][rc] = sm;
    const float mC = colmax[rc];
    float sc = 0.0f;
    #pragma unroll 8
    for (int r = q * 32; r < q * 32 + 32; ++r)
      sc += __expf(bf2f(score[r * SC_LD + rc]) - mC);
    part[1][q][rc] = sc;
  }
  __syncthreads();
  if (tid < SL) {
    rowinv[tid] = 1.0f / (part[0][0][tid] + part[0][1][tid] + part[0][2][tid] + part[0][3][tid]);
  } else if (tid < 2 * SL) {
    const int c = tid - SL;
    colinv[c] = 1.0f / (part[1][0][c] + part[1][1][c] + part[1][2][c] + part[1][3][c]);
  }
  __syncthreads();

  for (int idx = tid; idx < SL * SL; idx += 512) {
    const int r = idx >> 7, c = idx & 127;
    const float tv = __expf(bf2f(score[r * SC_LD + c]) - rowmax[r]) * rowinv[r];
    const float av = __expf(bf2f(score[c * SC_LD + r]) - colmax[r]) * colinv[r];
    __builtin_nontemporal_store(tv, &ta_base[idx]);
    __builtin_nontemporal_store(av, &at_base[idx]);
    if (use_p16) {
      taP[idx] = f2bf(tv);
      atP[idx] = f2bf(av);
    }
  }
}

// ---------------- K3: PV GEMM ----------------
__global__ __launch_bounds__(256) void pv_kernel(
    float* __restrict__ out, u16* __restrict__ ws16, int use_ws, int use_p16)
{
  // union: V^T tile (u16 [128][138] = 35,328B) during MFMA; fp32 [128][72] = 36,864B epilogue
  __shared__ __align__(16) float sbuf[SL * SB_LD];
  u16* const vt = (u16*)sbuf;

  const int raw = blockIdx.x;
  const int bid = (raw & 7) * 512 + (raw >> 3);  // bijective: 4096 % 8 == 0
  const int ntile = bid & 7;
  const int b = (bid >> 3) & 255;
  const int ori = bid >> 11;
  const int tid = threadIdx.x;
  const int lane = tid & 63;
  const int w = tid >> 6;

  const float* p_base = out + (ori ? OFF_ATSM : OFF_TASM) + (size_t)b * SL * SL;
  const u16* p16_base = ws16 + 2 * SIDE_ELEMS + (ori ? PHALF : (size_t)0) + (size_t)b * SL * SL;
  float* att_base = out + (ori ? OFF_TATT : OFF_SATT) + (size_t)b * SL * DIM + ntile * 128;

  // stage V^T tile; VT_LD=138 -> oct groups at banks +0/+8/+16/+24 (free)
  #pragma unroll
  for (int j = 0; j < 8; ++j) {
    const int idx = tid + j * 256;
    const int k = (idx & 15) | ((idx >> 8) << 4);
    const int oct = (idx >> 4) & 15;
    if (use_ws) {
      const u16* src = ws16 + (ori ? SIDE_ELEMS : 0)
                     + ((size_t)b * SL + k) * DIM + ntile * 128 + oct * 8;
      uint4 v = *(const uint4*)src;
      const u16* ev = (const u16*)&v;
      #pragma unroll
      for (int i = 0; i < 8; ++i) vt[(oct * 8 + i) * VT_LD + k] = ev[i];
    } else {
      const float* src = out + (ori ? OFF_T : OFF_S)
                       + ((size_t)b * SL + k) * DIM + ntile * 128 + oct * 8;
      float4 v0 = ((const float4*)src)[0];
      float4 v1 = ((const float4*)src)[1];
      vt[(oct * 8 + 0) * VT_LD + k] = f2bf(v0.x);
      vt[(oct * 8 + 1) * VT_LD + k] = f2bf(v0.y);
      vt[(oct * 8 + 2) * VT_LD + k] = f2bf(v0.z);
      vt[(oct * 8 + 3) * VT_LD + k] = f2bf(v0.w);
      vt[(oct * 8 + 4) * VT_LD + k] = f2bf(v1.x);
      vt[(oct * 8 + 5) * VT_LD + k] = f2bf(v1.y);
      vt[(oct * 8 + 6) * VT_LD + k] = f2bf(v1.z);
      vt[(oct * 8 + 7) * VT_LD + k] = f2bf(v1.w);
    }
  }

  // A-fragments (P): single 16B bf16 loads from sidecar (L2/L3-hot)
  bf16x8 afr[2][4];
  #pragma unroll
  for (int mt = 0; mt < 2; ++mt) {
    const int m = w * 32 + mt * 16 + (lane & 15);
    #pragma unroll
    for (int ks = 0; ks < 4; ++ks) {
      const int k0 = ks * 32 + (lane >> 4) * 8;
      if (use_p16) {
        afr[mt][ks] = *(const bf16x8*)(p16_base + (size_t)m * SL + k0);
      } else {
        const float* pp = p_base + (size_t)m * SL + k0;
        float4 x0 = ((const float4*)pp)[0];
        float4 x1 = ((const float4*)pp)[1];
        bf16x8 a;
        a[0] = (short)f2bf(x0.x); a[1] = (short)f2bf(x0.y);
        a[2] = (short)f2bf(x0.z); a[3] = (short)f2bf(x0.w);
        a[4] = (short)f2bf(x1.x); a[5] = (short)f2bf(x1.y);
        a[6] = (short)f2bf(x1.z); a[7] = (short)f2bf(x1.w);
        afr[mt][ks] = a;
      }
    }
  }
  __syncthreads();

  f32x4 acc[2][8];
  #pragma unroll
  for (int mt = 0; mt < 2; ++mt)
    #pragma unroll
    for (int nt = 0; nt < 8; ++nt)
      acc[mt][nt] = (f32x4){0.f, 0.f, 0.f, 0.f};

  const int colb = (lane >> 4) * 8;
  #pragma unroll
  for (int ks = 0; ks < 4; ++ks) {
    #pragma unroll
    for (int nt = 0; nt < 8; ++nt) {
      const bf16x8 bfr = *(const bf16x8*)&vt[(nt * 16 + (lane & 15)) * VT_LD + ks * 32 + colb];
      acc[0][nt] = __builtin_amdgcn_mfma_f32_16x16x32_bf16(afr[0][ks], bfr, acc[0][nt], 0, 0, 0);
      acc[1][nt] = __builtin_amdgcn_mfma_f32_16x16x32_bf16(afr[1][ks], bfr, acc[1][nt], 0, 0, 0);
    }
  }
  __syncthreads();   // all vt reads done; sbuf reuse below

  // ---- epilogue: acc -> LDS -> float4 NT stores (2 passes of 64 cols) ----
  #pragma unroll
  for (int pass = 0; pass < 2; ++pass) {
    #pragma unroll
    for (int mt = 0; mt < 2; ++mt)
      #pragma unroll
      for (int nq = 0; nq < 4; ++nq) {
        const int nt = pass * 4 + nq;
        const int col = nq * 16 + (lane & 15);
        const int rowb = w * 32 + mt * 16 + (lane >> 4) * 4;
        #pragma unroll
        for (int j = 0; j < 4; ++j)
          sbuf[(rowb + j) * SB_LD + col] = acc[mt][nt][j];
      }
    __syncthreads();
    #pragma unroll
    for (int j = 0; j < 8; ++j) {
      const int idx = tid + j * 256;   // 2048 float4 units: row(128) x c4(16)
      const int row = idx >> 4;
      const int c4 = idx & 15;
      const float* sp = &sbuf[row * SB_LD + c4 * 4];
      f32x4 v4; v4[0] = sp[0]; v4[1] = sp[1]; v4[2] = sp[2]; v4[3] = sp[3];
      __builtin_nontemporal_store(v4,
          (f32x4*)(att_base + (size_t)row * DIM + pass * 64) + c4);
    }
    if (pass == 0) __syncthreads();
  }
}

extern "C" void kernel_launch(void* const* d_in, const int* in_sizes, int n_in,
                              void* d_out, int out_size, void* d_ws, size_t ws_size,
                              hipStream_t stream) {
  const int* ssent = (const int*)d_in[0];
  const int* tsent = (const int*)d_in[1];
  const int* smask = (const int*)d_in[2];
  const int* tmask = (const int*)d_in[3];
  const float* semb = (const float*)d_in[4];
  const float* temb = (const float*)d_in[5];
  float* out = (float*)d_out;
  u16* ws16 = (u16*)d_ws;
  const int use_ws = (ws_size >= WS_NEEDED) ? 1 : 0;
  const int use_p16 = (ws_size >= WS_P_NEEDED) ? 1 : 0;

  hipLaunchKernelGGL(pool_kernel, dim3(4096), dim3(256), 0, stream,
                     ssent, tsent, semb, temb, out, ws16, use_ws);
  hipLaunchKernelGGL(score_kernel, dim3(256), dim3(512), 0, stream,
                     smask, tmask, out, ws16, use_ws, use_p16);
  hipLaunchKernelGGL(pv_kernel, dim3(4096), dim3(256), 0, stream, out, ws16, use_ws, use_p16);
}

// Round 14
// 245.175 us; speedup vs baseline: 1.3442x; 1.0882x over previous
//
#include <hip/hip_runtime.h>
#include <hip/hip_bf16.h>
#include <stdint.h>

// SynAlign R14: exact R9 pipeline, except K3 runs 512 threads (8 waves) per block:
// same tile, same LDS, same traffic -> 32 waves/CU resident (was 16) for latency hiding.
//  K1 pool_kernel : 4096 blocks (XCD-swizzled), 16 rows/block rolling window.
//  K2 score_kernel: 256 blocks x 512 thr, dk=64, score overlays chunk pool, dual softmax.
//  K3 pv_kernel   : 4096 blocks x 512 thr (XCD-swizzled), VT_LD=138, P16 A-frags, NT stores.

#define SL 128
#define DIM 1024

#define OFF_S     ((size_t)0)
#define OFF_SATT  ((size_t)33554432)
#define OFF_ATSM  ((size_t)67108864)
#define OFF_T     ((size_t)71303168)
#define OFF_TATT  ((size_t)104857600)
#define OFF_TASM  ((size_t)138412032)
#define SIDE_ELEMS ((size_t)33554432)           // bf16 sidecar elems per side
#define PHALF      ((size_t)4194304)            // elems per bf16 soft matrix
#define WS_NEEDED   ((size_t)134217728)         // s/t sidecar bytes
#define WS_P_NEEDED ((size_t)150994944)         // + P sidecar

typedef short bf16x8 __attribute__((ext_vector_type(8)));
typedef float f32x4 __attribute__((ext_vector_type(4)));
typedef unsigned short u16;

#define CH2   72   // K2 chunk row stride (bf16): 64 data + 8 pad
#define SC_LD 136  // score row stride (bf16): 128 data + 8 pad
#define VT_LD 138  // K3 V^T row stride (bf16): conflict-free staging writes

__device__ __forceinline__ u16 f2bf(float f) {
  union { float f; uint32_t u; } v; v.f = f;
  uint32_t r = (v.u + 0x7FFFu + ((v.u >> 16) & 1u)) >> 16;  // RNE
  return (u16)r;
}
__device__ __forceinline__ float bf2f(u16 h) {
  union { uint32_t u; float f; } v; v.u = ((uint32_t)h) << 16;
  return v.f;
}

// ---------------- K1: gather + avgpool3, 16 rows/block rolling window ----------------
__global__ __launch_bounds__(256) void pool_kernel(
    const int* __restrict__ ssent, const int* __restrict__ tsent,
    const float* __restrict__ semb, const float* __restrict__ temb,
    float* __restrict__ out, u16* __restrict__ ws16, int use_ws)
{
  const int raw = blockIdx.x;
  const int bid = (raw & 7) * 512 + (raw >> 3);   // XCD swizzle (4096 % 8 == 0)
  const int side = bid >> 11;
  const int rem = bid & 2047;
  const int b = rem >> 3;
  const int l0 = (rem & 7) * 16;
  const int tid = threadIdx.x;

  const int* __restrict__ sent = side ? tsent : ssent;
  const float* __restrict__ emb = side ? temb : semb;
  float* __restrict__ dst0 = out + (side ? OFF_T : OFF_S) + ((size_t)b * SL + l0) * DIM;
  u16* __restrict__ d16_0 = ws16 + (side ? SIDE_ELEMS : 0) + ((size_t)b * SL + l0) * DIM;

  const int sbase = b * SL + l0;
  float4 ePrev, eCur, eNext;
  if (l0 > 0) ePrev = ((const float4*)(emb + (size_t)sent[sbase - 1] * DIM))[tid];
  else        ePrev = (float4){0.f, 0.f, 0.f, 0.f};
  eCur = ((const float4*)(emb + (size_t)sent[sbase] * DIM))[tid];

  #pragma unroll
  for (int i = 0; i < 16; ++i) {
    const int l = l0 + i;
    if (l + 1 < SL)
      eNext = ((const float4*)(emb + (size_t)sent[sbase + i + 1] * DIM))[tid];
    else
      eNext = (float4){0.f, 0.f, 0.f, 0.f};
    const float scl = (l == 0 || l == SL - 1) ? 0.5f : (1.0f / 3.0f);
    f32x4 o;
    o[0] = (ePrev.x + eCur.x + eNext.x) * scl;
    o[1] = (ePrev.y + eCur.y + eNext.y) * scl;
    o[2] = (ePrev.z + eCur.z + eNext.z) * scl;
    o[3] = (ePrev.w + eCur.w + eNext.w) * scl;
    __builtin_nontemporal_store(o, ((f32x4*)(dst0 + (size_t)i * DIM)) + tid);
    if (use_ws) {
      ushort4 h;
      h.x = f2bf(o[0]); h.y = f2bf(o[1]); h.z = f2bf(o[2]); h.w = f2bf(o[3]);
      ((ushort4*)(d16_0 + (size_t)i * DIM))[tid] = h;   // cached: re-read by K2/K3
    }
    ePrev = eCur; eCur = eNext;
  }
}

// ---------------- K2: score (once) + dual softmax, dk=64 ----------------
__global__ __launch_bounds__(512) void score_kernel(
    const int* __restrict__ smask, const int* __restrict__ tmask,
    float* __restrict__ out, u16* __restrict__ ws16, int use_ws, int use_p16)
{
  // chunk pool (36,864 B); score [SL][SC_LD] (34,816 B) OVERLAYS it after the K-loop
  __shared__ __align__(16) u16 chunkpool[2 * SL * CH2];
  __shared__ float part[2][4][SL];
  __shared__ float rowmax[SL], rowinv[SL], colmax[SL], colinv[SL];
  __shared__ float maskT[SL], maskS[SL];

  u16* const a_chunk = chunkpool;             // t rows [SL][CH2]
  u16* const b_chunk = chunkpool + SL * CH2;  // s rows [SL][CH2]
  u16* const score   = chunkpool;             // [SL][SC_LD] after K-loop

  const int b = blockIdx.x;
  const int tid = threadIdx.x;
  const int lane = tid & 63;
  const int w = tid >> 6;

  const float* t_base = out + OFF_T + (size_t)b * SL * DIM;
  const float* s_base = out + OFF_S + (size_t)b * SL * DIM;
  float* ta_base = out + OFF_TASM + (size_t)b * SL * SL;
  float* at_base = out + OFF_ATSM + (size_t)b * SL * SL;
  u16* taP = ws16 + 2 * SIDE_ELEMS + (size_t)b * SL * SL;
  u16* atP = ws16 + 2 * SIDE_ELEMS + PHALF + (size_t)b * SL * SL;

  if (tid < SL) maskT[tid] = (tmask[b * SL + tid] != 0) ? 1.0f : 0.0f;
  else if (tid < 2 * SL) maskS[tid - SL] = (smask[b * SL + (tid - SL)] != 0) ? 1.0f : 0.0f;

  f32x4 acc[8];
  #pragma unroll
  for (int nt = 0; nt < 8; ++nt) acc[nt] = (f32x4){0.f, 0.f, 0.f, 0.f};

  const int srow = tid >> 2;        // 0..127
  const int seg = tid & 3;          // 0..3
  const size_t a_src = SIDE_ELEMS + ((size_t)b * SL + srow) * DIM + seg * 8;  // t
  const size_t b_src = ((size_t)b * SL + srow) * DIM + seg * 8;               // s
  u16* const a_dst = &a_chunk[srow * CH2 + seg * 8];
  u16* const b_dst = &b_chunk[srow * CH2 + seg * 8];

  uint4 ra0, ra1, rb0, rb1;

  if (use_ws) {
    ra0 = *(const uint4*)(ws16 + a_src);
    ra1 = *(const uint4*)(ws16 + a_src + 32);
    rb0 = *(const uint4*)(ws16 + b_src);
    rb1 = *(const uint4*)(ws16 + b_src + 32);
  }

  for (int it = 0; it < 16; ++it) {
    const int dk = it * 64;
    if (use_ws) {
      *(uint4*)a_dst = ra0;
      *(uint4*)(a_dst + 32) = ra1;
      *(uint4*)b_dst = rb0;
      *(uint4*)(b_dst + 32) = rb1;
    } else {
      #pragma unroll
      for (int c = 0; c < 2; ++c) {
        const float* ap = t_base + (size_t)srow * DIM + dk + c * 32 + seg * 8;
        const float* bp = s_base + (size_t)srow * DIM + dk + c * 32 + seg * 8;
        float4 va0 = ((const float4*)ap)[0], va1 = ((const float4*)ap)[1];
        float4 vb0 = ((const float4*)bp)[0], vb1 = ((const float4*)bp)[1];
        bf16x8 ha, hb;
        ha[0]=(short)f2bf(va0.x); ha[1]=(short)f2bf(va0.y); ha[2]=(short)f2bf(va0.z); ha[3]=(short)f2bf(va0.w);
        ha[4]=(short)f2bf(va1.x); ha[5]=(short)f2bf(va1.y); ha[6]=(short)f2bf(va1.z); ha[7]=(short)f2bf(va1.w);
        hb[0]=(short)f2bf(vb0.x); hb[1]=(short)f2bf(vb0.y); hb[2]=(short)f2bf(vb0.z); hb[3]=(short)f2bf(vb0.w);
        hb[4]=(short)f2bf(vb1.x); hb[5]=(short)f2bf(vb1.y); hb[6]=(short)f2bf(vb1.z); hb[7]=(short)f2bf(vb1.w);
        *(bf16x8*)(a_dst + c * 32) = ha;
        *(bf16x8*)(b_dst + c * 32) = hb;
      }
    }
    __syncthreads();

    if (use_ws && it + 1 < 16) {   // prefetch next chunk, hides under ds_read+MFMA
      const int dk2 = dk + 64;
      ra0 = *(const uint4*)(ws16 + a_src + dk2);
      ra1 = *(const uint4*)(ws16 + a_src + dk2 + 32);
      rb0 = *(const uint4*)(ws16 + b_src + dk2);
      rb1 = *(const uint4*)(ws16 + b_src + dk2 + 32);
    }

    #pragma unroll
    for (int ks = 0; ks < 2; ++ks) {
      const int colb = ks * 32 + (lane >> 4) * 8;
      const bf16x8 afr = *(const bf16x8*)&a_chunk[(w * 16 + (lane & 15)) * CH2 + colb];
      #pragma unroll
      for (int nt = 0; nt < 8; ++nt) {
        const bf16x8 bfr = *(const bf16x8*)&b_chunk[(nt * 16 + (lane & 15)) * CH2 + colb];
        acc[nt] = __builtin_amdgcn_mfma_f32_16x16x32_bf16(afr, bfr, acc[nt], 0, 0, 0);
      }
    }
    __syncthreads();
  }

  // masked score -> LDS (overlays dead chunk pool). col=lane&15, row=(lane>>4)*4+j
  #pragma unroll
  for (int nt = 0; nt < 8; ++nt) {
    const int coln = nt * 16 + (lane & 15);
    const float cm = maskS[coln];
    #pragma unroll
    for (int j = 0; j < 4; ++j) {
      const int rowm = w * 16 + (lane >> 4) * 4 + j;
      const float val = (cm != 0.0f && maskT[rowm] != 0.0f) ? acc[nt][j] : -999.0f;
      score[rowm * SC_LD + coln] = f2bf(val);
    }
  }
  __syncthreads();

  // ---- parallel 4-way softmax stats ----
  const int rc = tid & 127;
  const int q = tid >> 7;
  {
    float mx = -1e30f;
    #pragma unroll
    for (int c8 = 0; c8 < 4; ++c8) {
      const uint4 v = *(const uint4*)&score[rc * SC_LD + q * 32 + c8 * 8];
      mx = fmaxf(mx, fmaxf(bf2f((u16)(v.x & 0xffff)), bf2f((u16)(v.x >> 16))));
      mx = fmaxf(mx, fmaxf(bf2f((u16)(v.y & 0xffff)), bf2f((u16)(v.y >> 16))));
      mx = fmaxf(mx, fmaxf(bf2f((u16)(v.z & 0xffff)), bf2f((u16)(v.z >> 16))));
      mx = fmaxf(mx, fmaxf(bf2f((u16)(v.w & 0xffff)), bf2f((u16)(v.w >> 16))));
    }
    part[0][q][rc] = mx;
    float mc = -1e30f;
    #pragma unroll 8
    for (int r = q * 32; r < q * 32 + 32; ++r)
      mc = fmaxf(mc, bf2f(score[r * SC_LD + rc]));
    part[1][q][rc] = mc;
  }
  __syncthreads();
  if (tid < SL) {
    rowmax[tid] = fmaxf(fmaxf(part[0][0][tid], part[0][1][tid]),
                        fmaxf(part[0][2][tid], part[0][3][tid]));
  } else if (tid < 2 * SL) {
    const int c = tid - SL;
    colmax[c] = fmaxf(fmaxf(part[1][0][c], part[1][1][c]),
                      fmaxf(part[1][2][c], part[1][3][c]));
  }
  __syncthreads();
  {
    const float mR = rowmax[rc];
    float sm = 0.0f;
    #pragma unroll
    for (int c8 = 0; c8 < 4; ++c8) {
      const uint4 v = *(const uint4*)&score[rc * SC_LD + q * 32 + c8 * 8];
      sm += __expf(bf2f((u16)(v.x & 0xffff)) - mR) + __expf(bf2f((u16)(v.x >> 16)) - mR);
      sm += __expf(bf2f((u16)(v.y & 0xffff)) - mR) + __expf(bf2f((u16)(v.y >> 16)) - mR);
      sm += __expf(bf2f((u16)(v.z & 0xffff)) - mR) + __expf(bf2f((u16)(v.z >> 16)) - mR);
      sm += __expf(bf2f((u16)(v.w & 0xffff)) - mR) + __expf(bf2f((u16)(v.w >> 16)) - mR);
    }
    part[0][q][rc] = sm;
    const float mC = colmax[rc];
    float sc = 0.0f;
    #pragma unroll 8
    for (int r = q * 32; r < q * 32 + 32; ++r)
      sc += __expf(bf2f(score[r * SC_LD + rc]) - mC);
    part[1][q][rc] = sc;
  }
  __syncthreads();
  if (tid < SL) {
    rowinv[tid] = 1.0f / (part[0][0][tid] + part[0][1][tid] + part[0][2][tid] + part[0][3][tid]);
  } else if (tid < 2 * SL) {
    const int c = tid - SL;
    colinv[c] = 1.0f / (part[1][0][c] + part[1][1][c] + part[1][2][c] + part[1][3][c]);
  }
  __syncthreads();

  for (int idx = tid; idx < SL * SL; idx += 512) {
    const int r = idx >> 7, c = idx & 127;
    const float tv = __expf(bf2f(score[r * SC_LD + c]) - rowmax[r]) * rowinv[r];
    const float av = __expf(bf2f(score[c * SC_LD + r]) - colmax[r]) * colinv[r];
    __builtin_nontemporal_store(tv, &ta_base[idx]);
    __builtin_nontemporal_store(av, &at_base[idx]);
    if (use_p16) {
      taP[idx] = f2bf(tv);
      atP[idx] = f2bf(av);
    }
  }
}

// ---------------- K3: PV GEMM, 512 threads (8 waves, 16 rows each) ----------------
__global__ __launch_bounds__(512) void pv_kernel(
    float* __restrict__ out, u16* __restrict__ ws16, int use_ws, int use_p16)
{
  __shared__ __align__(16) u16 vt[SL * VT_LD];   // V^T [n][k], 35,328 B

  const int raw = blockIdx.x;
  const int bid = (raw & 7) * 512 + (raw >> 3);  // bijective: 4096 % 8 == 0
  const int ntile = bid & 7;
  const int b = (bid >> 3) & 255;
  const int ori = bid >> 11;
  const int tid = threadIdx.x;
  const int lane = tid & 63;
  const int w = tid >> 6;        // 0..7

  const float* p_base = out + (ori ? OFF_ATSM : OFF_TASM) + (size_t)b * SL * SL;
  const u16* p16_base = ws16 + 2 * SIDE_ELEMS + (ori ? PHALF : (size_t)0) + (size_t)b * SL * SL;
  float* att_base = out + (ori ? OFF_TATT : OFF_SATT) + (size_t)b * SL * DIM + ntile * 128;

  // stage V^T tile (2048 uint4 units over 512 thr = 4 iters); VT_LD=138 -> free writes
  #pragma unroll
  for (int j = 0; j < 4; ++j) {
    const int idx = tid + j * 512;            // [0,2048): k_low(16) x oct(16) x k_high(8)
    const int k = (idx & 15) | ((idx >> 8) << 4);
    const int oct = (idx >> 4) & 15;
    if (use_ws) {
      const u16* src = ws16 + (ori ? SIDE_ELEMS : 0)
                     + ((size_t)b * SL + k) * DIM + ntile * 128 + oct * 8;
      uint4 v = *(const uint4*)src;
      const u16* ev = (const u16*)&v;
      #pragma unroll
      for (int i = 0; i < 8; ++i) vt[(oct * 8 + i) * VT_LD + k] = ev[i];
    } else {
      const float* src = out + (ori ? OFF_T : OFF_S)
                       + ((size_t)b * SL + k) * DIM + ntile * 128 + oct * 8;
      float4 v0 = ((const float4*)src)[0];
      float4 v1 = ((const float4*)src)[1];
      vt[(oct * 8 + 0) * VT_LD + k] = f2bf(v0.x);
      vt[(oct * 8 + 1) * VT_LD + k] = f2bf(v0.y);
      vt[(oct * 8 + 2) * VT_LD + k] = f2bf(v0.z);
      vt[(oct * 8 + 3) * VT_LD + k] = f2bf(v0.w);
      vt[(oct * 8 + 4) * VT_LD + k] = f2bf(v1.x);
      vt[(oct * 8 + 5) * VT_LD + k] = f2bf(v1.y);
      vt[(oct * 8 + 6) * VT_LD + k] = f2bf(v1.z);
      vt[(oct * 8 + 7) * VT_LD + k] = f2bf(v1.w);
    }
  }

  // A-fragments (P): wave w owns rows [16w, 16w+16); single 16B bf16 loads (L2/L3-hot)
  bf16x8 afr[4];
  const int m = w * 16 + (lane & 15);
  #pragma unroll
  for (int ks = 0; ks < 4; ++ks) {
    const int k0 = ks * 32 + (lane >> 4) * 8;
    if (use_p16) {
      afr[ks] = *(const bf16x8*)(p16_base + (size_t)m * SL + k0);
    } else {
      const float* pp = p_base + (size_t)m * SL + k0;
      float4 x0 = ((const float4*)pp)[0];
      float4 x1 = ((const float4*)pp)[1];
      bf16x8 a;
      a[0] = (short)f2bf(x0.x); a[1] = (short)f2bf(x0.y);
      a[2] = (short)f2bf(x0.z); a[3] = (short)f2bf(x0.w);
      a[4] = (short)f2bf(x1.x); a[5] = (short)f2bf(x1.y);
      a[6] = (short)f2bf(x1.z); a[7] = (short)f2bf(x1.w);
      afr[ks] = a;
    }
  }
  __syncthreads();

  f32x4 acc[8];
  #pragma unroll
  for (int nt = 0; nt < 8; ++nt) acc[nt] = (f32x4){0.f, 0.f, 0.f, 0.f};

  const int colb = (lane >> 4) * 8;
  #pragma unroll
  for (int ks = 0; ks < 4; ++ks) {
    #pragma unroll
    for (int nt = 0; nt < 8; ++nt) {
      const bf16x8 bfr = *(const bf16x8*)&vt[(nt * 16 + (lane & 15)) * VT_LD + ks * 32 + colb];
      acc[nt] = __builtin_amdgcn_mfma_f32_16x16x32_bf16(afr[ks], bfr, acc[nt], 0, 0, 0);
    }
  }

  #pragma unroll
  for (int nt = 0; nt < 8; ++nt) {
    const int rowm = w * 16 + (lane >> 4) * 4;
    #pragma unroll
    for (int j = 0; j < 4; ++j)
      __builtin_nontemporal_store(acc[nt][j],
          &att_base[(size_t)(rowm + j) * DIM + nt * 16 + (lane & 15)]);
  }
}

extern "C" void kernel_launch(void* const* d_in, const int* in_sizes, int n_in,
                              void* d_out, int out_size, void* d_ws, size_t ws_size,
                              hipStream_t stream) {
  const int* ssent = (const int*)d_in[0];
  const int* tsent = (const int*)d_in[1];
  const int* smask = (const int*)d_in[2];
  const int* tmask = (const int*)d_in[3];
  const float* semb = (const float*)d_in[4];
  const float* temb = (const float*)d_in[5];
  float* out = (float*)d_out;
  u16* ws16 = (u16*)d_ws;
  const int use_ws = (ws_size >= WS_NEEDED) ? 1 : 0;
  const int use_p16 = (ws_size >= WS_P_NEEDED) ? 1 : 0;

  hipLaunchKernelGGL(pool_kernel, dim3(4096), dim3(256), 0, stream,
                     ssent, tsent, semb, temb, out, ws16, use_ws);
  hipLaunchKernelGGL(score_kernel, dim3(256), dim3(512), 0, stream,
                     smask, tmask, out, ws16, use_ws, use_p16);
  hipLaunchKernelGGL(pv_kernel, dim3(4096), dim3(512), 0, stream, out, ws16, use_ws, use_p16);
}